// Round 6
// baseline (572.243 us; speedup 1.0000x reference)
//
#include <hip/hip_runtime.h>
#include <hip/hip_bf16.h>

typedef unsigned short u16;
typedef __attribute__((ext_vector_type(8))) short short8;
typedef __attribute__((ext_vector_type(4))) short short4v;
typedef __attribute__((ext_vector_type(4))) float f32x4;
typedef __attribute__((ext_vector_type(4))) int int4v;

typedef const __attribute__((address_space(1))) void* gas1;
typedef __attribute__((address_space(3))) void* las3;

#define B_   4
#define S_   1024
#define D_   1024
#define H_   16
#define DH_  64
#define NOUT_ ((size_t)B_ * S_ * D_)   // 4,194,304 out elems; attn follows in d_out
#define NQ_  4194304                   // elems in q/k/v (and each [B,H,S,64] tensor)
#define NW_  1048576                   // elems in each weight matrix

__device__ __forceinline__ float b2f(u16 u) {
  union { unsigned int u; float f; } v; v.u = ((unsigned int)u) << 16; return v.f;
}
__device__ __forceinline__ u16 f2b(float f) {
  __hip_bfloat16 h = __float2bfloat16(f);
  return *reinterpret_cast<u16*>(&h);
}

// ---------------------------------------------------------------------------
// K0: weights fp32->bf16 (y=0..3, 512 blocks) + mask packing (y=4, 2048
// blocks). q/k/v conversion REMOVED: proj stages activations from fp32
// inline (saves the 48MB read + 24MB write + 24MB re-read round trip).
// ---------------------------------------------------------------------------
__global__ __launch_bounds__(256) void convert_kernel(
    const float* __restrict__ wq, const float* __restrict__ wk,
    const float* __restrict__ wv, const float* __restrict__ wd,
    const int* __restrict__ mask,
    u16* __restrict__ wqb, u16* __restrict__ wkb, u16* __restrict__ wvb,
    u16* __restrict__ wdb, unsigned char* __restrict__ pm)
{
  if (blockIdx.y == 4) {
    size_t bi = (size_t)blockIdx.x * 256 + threadIdx.x;   // output byte index
    const int* mp = mask + bi * 8;
    int4v m0 = __builtin_nontemporal_load((const int4v*)mp);
    int4v m1 = __builtin_nontemporal_load((const int4v*)(mp + 4));
    unsigned bm = (unsigned)(m0[0] != 0)        | ((unsigned)(m0[1] != 0) << 1)
                | ((unsigned)(m0[2] != 0) << 2) | ((unsigned)(m0[3] != 0) << 3)
                | ((unsigned)(m1[0] != 0) << 4) | ((unsigned)(m1[1] != 0) << 5)
                | ((unsigned)(m1[2] != 0) << 6) | ((unsigned)(m1[3] != 0) << 7);
    pm[bi] = (unsigned char)bm;
    return;
  }
  if ((int)blockIdx.x >= 512) return;
  const float* src; u16* dst;
  switch (blockIdx.y) {
    case 0: src = wq; dst = wqb; break;
    case 1: src = wk; dst = wkb; break;
    case 2: src = wv; dst = wvb; break;
    default: src = wd; dst = wdb; break;
  }
  size_t idx = ((size_t)blockIdx.x * 256 + threadIdx.x) * 8;
  f32x4 f0 = __builtin_nontemporal_load((const f32x4*)&src[idx]);
  f32x4 f1 = __builtin_nontemporal_load((const f32x4*)&src[idx + 4]);
  short8 o;
  o[0] = (short)f2b(f0[0]); o[1] = (short)f2b(f0[1]);
  o[2] = (short)f2b(f0[2]); o[3] = (short)f2b(f0[3]);
  o[4] = (short)f2b(f1[0]); o[5] = (short)f2b(f1[1]);
  o[6] = (short)f2b(f1[2]); o[7] = (short)f2b(f1[3]);
  *(short8*)&dst[idx] = o;
}

// ---------------------------------------------------------------------------
// K1: fused Q/K/V projection, 128x128 tile, 4x4 16x16x32 accs per wave.
// A-operand staged DIRECTLY FROM FP32 q/k/v: 256 threads reg-stage the
// 128x64 tile (2x f32x4 load -> cvt -> one ds_write_b128 each, lane-linear
// 16B mapping => conflict-free). Same rounding as the old convert pass, so
// results are bit-identical. B-operand (weights) still bf16 global_load_lds.
// z<2 -> [B,H,S,64]; z==2 -> vhT [B,H,64,S] via SWAPPED MFMA operands.
// ---------------------------------------------------------------------------
__global__ __launch_bounds__(256) void proj_kernel(
    const float* __restrict__ Qf, const float* __restrict__ Kf, const float* __restrict__ Vf,
    const u16* __restrict__ Wqb, const u16* __restrict__ Wkb, const u16* __restrict__ Wvb,
    u16* __restrict__ qh, u16* __restrict__ kh, u16* __restrict__ vhT)
{
  __shared__ u16 sA[128][64];   // linear
  __shared__ u16 sB[128][64];   // linear: required by global_load_lds
  const int t = threadIdx.x;
  const int w = t >> 6, ln = t & 15, quad = (t & 63) >> 4;
  const int wm = (w >> 1) * 64, wn = (w & 1) * 64;
  const int bx = blockIdx.x;
  const int z  = bx >> 3;
  const int n0 = (bx & 7) * 128;
  const int m0 = blockIdx.y * 128;
  const float* A = (z == 0) ? Qf : (z == 1) ? Kf : Vf;
  const u16*   W = (z == 0) ? Wqb : (z == 1) ? Wkb : Wvb;
  const int lrow = (t & 63) >> 3;      // lane/8: row within 8-row group (B stage)
  const int lcol = (t & 7) * 8;        // (lane%8)*8: col elems (B stage)
  const int sr = t >> 3;               // 0..31: A-stage row within 32-row chunk
  const int sc = (t & 7) * 8;          // A-stage col

  f32x4 acc[4][4] = {};
  for (int kc = 0; kc < 1024; kc += 64) {
    // B: async bf16 staging (one dwordx4 per wave-row-group)
#pragma unroll
    for (int i = 0; i < 4; i++) {
      const int r0 = w * 32 + i * 8;   // wave w stages rows [w*32, w*32+32)
      __builtin_amdgcn_global_load_lds(
          (gas1)&W[(size_t)(n0 + r0 + lrow) * 1024 + kc + lcol],
          (las3)(void*)&sB[r0][0], 16, 0, 0);
    }
    // A: fp32 -> bf16 reg-staged; thread t covers rows {sr, sr+32, sr+64,
    // sr+96} x cols [sc, sc+8). ds_write addresses are lane-linear 16B.
#pragma unroll
    for (int kchunk = 0; kchunk < 4; kchunk++) {
      const int row = kchunk * 32 + sr;
      const float* ap = &A[(size_t)(m0 + row) * 1024 + kc + sc];
      f32x4 fa0 = *(const f32x4*)ap;
      f32x4 fa1 = *(const f32x4*)(ap + 4);
      short8 o;
      o[0] = (short)f2b(fa0[0]); o[1] = (short)f2b(fa0[1]);
      o[2] = (short)f2b(fa0[2]); o[3] = (short)f2b(fa0[3]);
      o[4] = (short)f2b(fa1[0]); o[5] = (short)f2b(fa1[1]);
      o[6] = (short)f2b(fa1[2]); o[7] = (short)f2b(fa1[3]);
      *(short8*)&sA[row][sc] = o;
    }
    asm volatile("s_waitcnt vmcnt(0)" ::: "memory");
    __syncthreads();
    if (z == 2) {
      // swapped operands: acc[i][j] = W_frag x A_frag
#pragma unroll
      for (int kk = 0; kk < 64; kk += 32) {
        short8 a[4], bfr[4];
#pragma unroll
        for (int i = 0; i < 4; i++) a[i] = *(const short8*)&sA[wm + i * 16 + ln][kk + quad * 8];
#pragma unroll
        for (int j = 0; j < 4; j++) bfr[j] = *(const short8*)&sB[wn + j * 16 + ln][kk + quad * 8];
#pragma unroll
        for (int i = 0; i < 4; i++)
#pragma unroll
          for (int j = 0; j < 4; j++)
            acc[i][j] = __builtin_amdgcn_mfma_f32_16x16x32_bf16(bfr[j], a[i], acc[i][j], 0, 0, 0);
      }
    } else {
#pragma unroll
      for (int kk = 0; kk < 64; kk += 32) {
        short8 a[4], bfr[4];
#pragma unroll
        for (int i = 0; i < 4; i++) a[i] = *(const short8*)&sA[wm + i * 16 + ln][kk + quad * 8];
#pragma unroll
        for (int j = 0; j < 4; j++) bfr[j] = *(const short8*)&sB[wn + j * 16 + ln][kk + quad * 8];
#pragma unroll
        for (int i = 0; i < 4; i++)
#pragma unroll
          for (int j = 0; j < 4; j++)
            acc[i][j] = __builtin_amdgcn_mfma_f32_16x16x32_bf16(a[i], bfr[j], acc[i][j], 0, 0, 0);
      }
    }
    __syncthreads();
  }
  if (z == 2) {
    // C mapping (swapped): row = quad*4+r -> channel n, col = ln -> token m
#pragma unroll
    for (int i = 0; i < 4; i++)
#pragma unroll
      for (int j = 0; j < 4; j++)
#pragma unroll
        for (int r = 0; r < 4; r++) {
          int n = n0 + wn + j * 16 + quad * 4 + r;   // channel
          int m = m0 + wm + i * 16 + ln;             // token (contiguous/lane)
          int bb = m >> 10, s = m & 1023, h = n >> 6, d = n & 63;
          vhT[(((size_t)bb * H_ + h) * DH_ + d) * S_ + s] = f2b(acc[i][j][r]);
        }
  } else {
#pragma unroll
    for (int i = 0; i < 4; i++)
#pragma unroll
      for (int j = 0; j < 4; j++)
#pragma unroll
        for (int r = 0; r < 4; r++) {
          int m = m0 + wm + i * 16 + quad * 4 + r;   // token
          int n = n0 + wn + j * 16 + ln;             // channel (contiguous/lane)
          int bb = m >> 10, s = m & 1023, h = n >> 6, d = n & 63;
          u16 val = f2b(acc[i][j][r]);
          if (z == 0) qh[(((size_t)bb * H_ + h) * S_ + s) * DH_ + d] = val;
          else        kh[(((size_t)bb * H_ + h) * S_ + s) * DH_ + d] = val;
        }
  }
}

// ---------------------------------------------------------------------------
// K2: attention, 16 q-rows/block, 4 waves, strip 33.5 KB => 4 blocks/CU.
// Grid 4096, XCD head-grouping: bh = (wg&7)*8 | (wg>>3)&7.
// A: swapped QK^T -> C[k_sub][q], one ds_write_b64 per MFMA pair.
// B: masked softmax from packed bitmap; NT store of fp32 probs.
// C: PV, dual accumulators; V-frags straight from vhT (L2-resident).
// ---------------------------------------------------------------------------
__global__ __launch_bounds__(256) void attn_kernel(
    const u16* __restrict__ qh, const u16* __restrict__ kh,
    const u16* __restrict__ vhT, const unsigned char* __restrict__ pmask,
    float* __restrict__ attn_out, u16* __restrict__ ctx)
{
  __shared__ u16 s_p[16][1048];   // 33.5 KB
  const int t = threadIdx.x;
  const int w = t >> 6, ln = t & 15, quad = (t & 63) >> 4;
  const int wg = blockIdx.x;
  const int bh = ((wg & 7) << 3) | ((wg >> 3) & 7);   // bijective XCD grouping
  const int b = bh >> 4, h = bh & 15;
  const int q0 = (wg >> 6) * 16;

  // Q B-fragments straight from global: row=ln (q-row), k=quad*8(+32)
  const u16* qbase = qh + ((size_t)bh * S_ + q0) * DH_;
  const short8 qf0 = *(const short8*)&qbase[(size_t)ln * DH_ + quad * 8];
  const short8 qf1 = *(const short8*)&qbase[(size_t)ln * DH_ + 32 + quad * 8];

  // ---- Phase A: scores; wave w owns k-cols [w*256, w*256+256) ----
  const u16* kbase = kh + (size_t)bh * S_ * DH_;
#pragma unroll
  for (int ck = 0; ck < 16; ck++) {
    int n = w * 256 + ck * 16;
    const u16* krow = &kbase[(size_t)(n + ln) * DH_];
    short8 kb0 = *(const short8*)&krow[quad * 8];
    short8 kb1 = *(const short8*)&krow[32 + quad * 8];
    f32x4 acc = {};
    acc = __builtin_amdgcn_mfma_f32_16x16x32_bf16(kb0, qf0, acc, 0, 0, 0);
    acc = __builtin_amdgcn_mfma_f32_16x16x32_bf16(kb1, qf1, acc, 0, 0, 0);
    // C[k_sub][q]: k = n + quad*4 + r (consecutive in r), q = ln
    short4v pk;
#pragma unroll
    for (int r = 0; r < 4; r++) pk[r] = (short)f2b(acc[r] * 0.03125f);
    *(short4v*)&s_p[ln][n + quad * 4] = pk;   // one b64 store
  }
  __syncthreads();

  // ---- Phase B: mask + softmax + attn output (16 threads per q-row) ----
  {
    const int r  = t >> 4;    // q-row 0..15
    const int cg = t & 15;    // column group: cols cg*8 + 128*i
    const unsigned char* mrow = pmask + ((size_t)b * S_ + q0 + r) * 128;
    const u16* prow = s_p[r];
    short8 sv[8];
    unsigned long long mbits = 0;
    float mx = -1e30f;
#pragma unroll
    for (int i = 0; i < 8; i++) {
      int c = cg * 8 + i * 128;
      sv[i] = *(const short8*)&prow[c];
      unsigned mb = mrow[cg + i * 16];          // packed: bit j = masked
      mbits |= ((unsigned long long)mb) << (i * 8);
#pragma unroll
      for (int j = 0; j < 8; j++) {
        float sval = b2f((u16)sv[i][j]);
        mx = fmaxf(mx, ((mb >> j) & 1) ? -1e30f : sval);   // branchless
      }
    }
#pragma unroll
    for (int off = 8; off >= 1; off >>= 1) mx = fmaxf(mx, __shfl_xor(mx, off));
    float l = 0.f;
#pragma unroll
    for (int i = 0; i < 8; i++) {
      short8 pk;
#pragma unroll
      for (int j = 0; j < 8; j++) {
        float p = ((mbits >> (i * 8 + j)) & 1) ? 0.f
                  : __expf(b2f((u16)sv[i][j]) - mx);
        l += p;
        pk[j] = (short)f2b(p);
      }
      sv[i] = pk;   // regs now hold p (bf16)
    }
#pragma unroll
    for (int off = 8; off >= 1; off >>= 1) l += __shfl_xor(l, off);
    float rinv = (l > 0.f) ? 1.0f / l : 0.f;
    float* arow = attn_out + ((size_t)bh * S_ + q0 + r) * S_;
    u16* prw = s_p[r];
#pragma unroll
    for (int i = 0; i < 8; i++) {
      int c = cg * 8 + i * 128;
      f32x4 o0, o1; short8 pn;
#pragma unroll
      for (int j = 0; j < 8; j++) {
        float pv = b2f((u16)sv[i][j]) * rinv;
        if (j < 4) o0[j] = pv; else o1[j - 4] = pv;
        pn[j] = (short)f2b(pv);
      }
      __builtin_nontemporal_store(o0, (f32x4*)&arow[c]);
      __builtin_nontemporal_store(o1, (f32x4*)&arow[c + 4]);
      *(short8*)&prw[c] = pn;
    }
  }
  __syncthreads();

  // ---- Phase C: ctx = attn @ vh; wave w owns out cols d in [w*16, w*16+16) --
  f32x4 accC0 = {}, accC1 = {};
  const u16* vrow = vhT + ((size_t)bh * DH_ + w * 16 + ln) * S_;
  const u16* prow = s_p[ln];
#pragma unroll 4
  for (int kk = 0; kk < 1024; kk += 64) {
    short8 ap0 = *(const short8*)&prow[kk + quad * 8];
    short8 ap1 = *(const short8*)&prow[kk + 32 + quad * 8];
    short8 bv0 = *(const short8*)&vrow[kk + quad * 8];
    short8 bv1 = *(const short8*)&vrow[kk + 32 + quad * 8];
    accC0 = __builtin_amdgcn_mfma_f32_16x16x32_bf16(ap0, bv0, accC0, 0, 0, 0);
    accC1 = __builtin_amdgcn_mfma_f32_16x16x32_bf16(ap1, bv1, accC1, 0, 0, 0);
  }
  f32x4 accC = accC0 + accC1;
#pragma unroll
  for (int r = 0; r < 4; r++) {
    int qrow = q0 + quad * 4 + r;
    ctx[((size_t)b * S_ + qrow) * D_ + h * DH_ + w * 16 + ln] = f2b(accC[r]);
  }
}

// ---------------------------------------------------------------------------
// K3: out = ctx @ Wd^T + bd (fp32 out, NT stores). m97-style GEMM skeleton.
// ---------------------------------------------------------------------------
__global__ __launch_bounds__(256) void outproj_kernel(
    const u16* __restrict__ ctx, const u16* __restrict__ Wdb,
    const float* __restrict__ bd, float* __restrict__ out)
{
  __shared__ u16 sA[128][64];
  __shared__ u16 sB[128][64];
  const int t = threadIdx.x;
  const int w = t >> 6, ln = t & 15, quad = (t & 63) >> 4;
  const int wm = (w >> 1) * 64, wn = (w & 1) * 64;
  const int n0 = blockIdx.x * 128;
  const int m0 = blockIdx.y * 128;
  const int lrow = (t & 63) >> 3;
  const int lcol = (t & 7) * 8;

  f32x4 acc[4][4] = {};
  for (int kc = 0; kc < 1024; kc += 64) {
#pragma unroll
    for (int i = 0; i < 4; i++) {
      const int r0 = w * 32 + i * 8;
      __builtin_amdgcn_global_load_lds(
          (gas1)&ctx[(size_t)(m0 + r0 + lrow) * 1024 + kc + lcol],
          (las3)(void*)&sA[r0][0], 16, 0, 0);
      __builtin_amdgcn_global_load_lds(
          (gas1)&Wdb[(size_t)(n0 + r0 + lrow) * 1024 + kc + lcol],
          (las3)(void*)&sB[r0][0], 16, 0, 0);
    }
    asm volatile("s_waitcnt vmcnt(0)" ::: "memory");
    __syncthreads();
#pragma unroll
    for (int kk = 0; kk < 64; kk += 32) {
      short8 a[4], bfr[4];
#pragma unroll
      for (int i = 0; i < 4; i++) a[i] = *(const short8*)&sA[wm + i * 16 + ln][kk + quad * 8];
#pragma unroll
      for (int j = 0; j < 4; j++) bfr[j] = *(const short8*)&sB[wn + j * 16 + ln][kk + quad * 8];
#pragma unroll
      for (int i = 0; i < 4; i++)
#pragma unroll
        for (int j = 0; j < 4; j++)
          acc[i][j] = __builtin_amdgcn_mfma_f32_16x16x32_bf16(a[i], bfr[j], acc[i][j], 0, 0, 0);
    }
    __syncthreads();
  }
#pragma unroll
  for (int i = 0; i < 4; i++)
#pragma unroll
    for (int j = 0; j < 4; j++)
#pragma unroll
      for (int r = 0; r < 4; r++) {
        int m = m0 + wm + i * 16 + quad * 4 + r;
        int n = n0 + wn + j * 16 + ln;
        __builtin_nontemporal_store(acc[i][j][r] + bd[n], &out[(size_t)m * 1024 + n]);
      }
}

extern "C" void kernel_launch(void* const* d_in, const int* in_sizes, int n_in,
                              void* d_out, int out_size, void* d_ws, size_t ws_size,
                              hipStream_t stream) {
  const float* q    = (const float*)d_in[0];
  const float* k    = (const float*)d_in[1];
  const float* v    = (const float*)d_in[2];
  const int*   mask = (const int*)d_in[3];
  const float* Wq   = (const float*)d_in[4];
  const float* Wk   = (const float*)d_in[5];
  const float* Wv   = (const float*)d_in[6];
  const float* Wd   = (const float*)d_in[7];
  const float* bd   = (const float*)d_in[8];

  float* out  = (float*)d_out;
  float* attn = out + NOUT_;

  u16* ws   = (u16*)d_ws;
  u16* Qb   = ws;                    // (slots kept for layout stability)
  u16* Wqb  = ws + 3 * (size_t)NQ_;  // 4x NW_ bf16 weights
  u16* Wkb  = Wqb + (size_t)NW_;
  u16* Wvb  = Wqb + 2 * (size_t)NW_;
  u16* Wdb  = Wqb + 3 * (size_t)NW_;
  u16* qh   = Wqb + 4 * (size_t)NW_; // 3x NQ_ projected tensors
  u16* kh   = qh + (size_t)NQ_;
  u16* vhT  = qh + 2 * (size_t)NQ_;
  unsigned char* pm = (unsigned char*)(qh + 3 * (size_t)NQ_);  // 512 KB bitmap
  u16* ctx  = Qb;                    // Qb region unused by compute now; reuse

  convert_kernel<<<dim3(2048, 5), 256, 0, stream>>>(Wq, Wk, Wv, Wd, mask,
                                                    Wqb, Wkb, Wvb, Wdb, pm);
  proj_kernel<<<dim3(24, 32), 256, 0, stream>>>(q, k, v, Wqb, Wkb, Wvb, qh, kh, vhT);
  attn_kernel<<<dim3(4096), 256, 0, stream>>>(qh, kh, vhT, pm, attn, ctx);
  outproj_kernel<<<dim3(8, 32), 256, 0, stream>>>(ctx, Wdb, bd, out);
}

// Round 7
// 517.958 us; speedup vs baseline: 1.1048x; 1.1048x over previous
//
#include <hip/hip_runtime.h>
#include <hip/hip_bf16.h>

typedef unsigned short u16;
typedef __attribute__((ext_vector_type(8))) short short8;
typedef __attribute__((ext_vector_type(4))) short short4v;
typedef __attribute__((ext_vector_type(4))) float f32x4;
typedef __attribute__((ext_vector_type(4))) int int4v;

typedef const __attribute__((address_space(1))) void* gas1;
typedef __attribute__((address_space(3))) void* las3;

#define B_   4
#define S_   1024
#define D_   1024
#define H_   16
#define DH_  64
#define NOUT_ ((size_t)B_ * S_ * D_)   // 4,194,304 out elems; attn follows in d_out
#define NQ_  4194304                   // elems in q/k/v (and each [B,H,S,64] tensor)
#define NW_  1048576                   // elems in each weight matrix

__device__ __forceinline__ float b2f(u16 u) {
  union { unsigned int u; float f; } v; v.u = ((unsigned int)u) << 16; return v.f;
}
__device__ __forceinline__ u16 f2b(float f) {
  __hip_bfloat16 h = __float2bfloat16(f);
  return *reinterpret_cast<u16*>(&h);
}

// ---------------------------------------------------------------------------
// K0: fp32 -> bf16 conversion of all inputs (one pass, coalesced) + mask
// packing. grid.y = segment (0..7): q,k,v (2048 blocks) / Wq,Wk,Wv,Wd (512) /
// mask->bitmap (2048). Convert pass RESTORED (R6 lesson: proj re-reads each
// A panel 8x; converting once here amortizes — inline fp32 staging cost +50us).
// Mask bytes stored PERMUTED within each 128B row: pmT[row][cg*8+i] =
// orig[row][cg+16i], so attn phase B does ONE b64 load = mbits verbatim.
// ---------------------------------------------------------------------------
__global__ __launch_bounds__(256) void convert_kernel(
    const float* __restrict__ q, const float* __restrict__ k, const float* __restrict__ v,
    const float* __restrict__ wq, const float* __restrict__ wk,
    const float* __restrict__ wv, const float* __restrict__ wd,
    const int* __restrict__ mask,
    u16* __restrict__ qb, u16* __restrict__ kb, u16* __restrict__ vb,
    u16* __restrict__ wqb, u16* __restrict__ wkb, u16* __restrict__ wvb,
    u16* __restrict__ wdb, unsigned char* __restrict__ pm)
{
  if (blockIdx.y == 7) {
    size_t bi = (size_t)blockIdx.x * 256 + threadIdx.x;   // original byte index
    const int* mp = mask + bi * 8;
    int4v m0 = __builtin_nontemporal_load((const int4v*)mp);
    int4v m1 = __builtin_nontemporal_load((const int4v*)(mp + 4));
    unsigned bm = (unsigned)(m0[0] != 0)        | ((unsigned)(m0[1] != 0) << 1)
                | ((unsigned)(m0[2] != 0) << 2) | ((unsigned)(m0[3] != 0) << 3)
                | ((unsigned)(m1[0] != 0) << 4) | ((unsigned)(m1[1] != 0) << 5)
                | ((unsigned)(m1[2] != 0) << 6) | ((unsigned)(m1[3] != 0) << 7);
    // permute within the 128-byte row: col8 = cg + 16*i  ->  cg*8 + i
    size_t rowbase = bi & ~(size_t)127;
    int col8 = (int)(bi & 127);
    pm[rowbase | (size_t)(((col8 & 15) << 3) | (col8 >> 4))] = (unsigned char)bm;
    return;
  }
  const float* src; u16* dst; int nblk;
  switch (blockIdx.y) {
    case 0: src = q;  dst = qb;  nblk = 2048; break;
    case 1: src = k;  dst = kb;  nblk = 2048; break;
    case 2: src = v;  dst = vb;  nblk = 2048; break;
    case 3: src = wq; dst = wqb; nblk = 512;  break;
    case 4: src = wk; dst = wkb; nblk = 512;  break;
    case 5: src = wv; dst = wvb; nblk = 512;  break;
    default: src = wd; dst = wdb; nblk = 512; break;
  }
  if ((int)blockIdx.x >= nblk) return;
  size_t idx = ((size_t)blockIdx.x * 256 + threadIdx.x) * 8;
  f32x4 f0 = __builtin_nontemporal_load((const f32x4*)&src[idx]);
  f32x4 f1 = __builtin_nontemporal_load((const f32x4*)&src[idx + 4]);
  short8 o;
  o[0] = (short)f2b(f0[0]); o[1] = (short)f2b(f0[1]);
  o[2] = (short)f2b(f0[2]); o[3] = (short)f2b(f0[3]);
  o[4] = (short)f2b(f1[0]); o[5] = (short)f2b(f1[1]);
  o[6] = (short)f2b(f1[2]); o[7] = (short)f2b(f1[3]);
  *(short8*)&dst[idx] = o;
}

// ---------------------------------------------------------------------------
// K1: fused Q/K/V projection, 128x128 tile, 4x4 16x16x32 accs per wave.
// m97 structure: global_load_lds dwordx4 staging into LINEAR LDS [128][64].
// z<2 -> [B,H,S,64]; z==2 -> vhT [B,H,64,S] via SWAPPED MFMA operands
// (C row=reg->channel d, col=lane->token s => 16-lane contiguous stores).
// ---------------------------------------------------------------------------
__global__ __launch_bounds__(256) void proj_kernel(
    const u16* __restrict__ Qb, const u16* __restrict__ Kb, const u16* __restrict__ Vb,
    const u16* __restrict__ Wqb, const u16* __restrict__ Wkb, const u16* __restrict__ Wvb,
    u16* __restrict__ qh, u16* __restrict__ kh, u16* __restrict__ vhT)
{
  __shared__ u16 sA[128][64];   // linear: required by global_load_lds
  __shared__ u16 sB[128][64];
  const int t = threadIdx.x;
  const int w = t >> 6, ln = t & 15, quad = (t & 63) >> 4;
  const int wm = (w >> 1) * 64, wn = (w & 1) * 64;
  const int bx = blockIdx.x;
  const int z  = bx >> 3;
  const int n0 = (bx & 7) * 128;
  const int m0 = blockIdx.y * 128;
  const u16* A = (z == 0) ? Qb : (z == 1) ? Kb : Vb;
  const u16* W = (z == 0) ? Wqb : (z == 1) ? Wkb : Wvb;
  const int lrow = (t & 63) >> 3;      // lane/8: row within 8-row group
  const int lcol = (t & 7) * 8;        // (lane%8)*8: col elems

  f32x4 acc[4][4] = {};
  for (int kc = 0; kc < 1024; kc += 64) {
#pragma unroll
    for (int i = 0; i < 4; i++) {
      const int r0 = w * 32 + i * 8;   // wave w stages rows [w*32, w*32+32)
      __builtin_amdgcn_global_load_lds(
          (gas1)&A[(size_t)(m0 + r0 + lrow) * 1024 + kc + lcol],
          (las3)(void*)&sA[r0][0], 16, 0, 0);
      __builtin_amdgcn_global_load_lds(
          (gas1)&W[(size_t)(n0 + r0 + lrow) * 1024 + kc + lcol],
          (las3)(void*)&sB[r0][0], 16, 0, 0);
    }
    asm volatile("s_waitcnt vmcnt(0)" ::: "memory");
    __syncthreads();
    if (z == 2) {
      // swapped operands: acc[i][j] = W_frag x A_frag
#pragma unroll
      for (int kk = 0; kk < 64; kk += 32) {
        short8 a[4], bfr[4];
#pragma unroll
        for (int i = 0; i < 4; i++) a[i] = *(const short8*)&sA[wm + i * 16 + ln][kk + quad * 8];
#pragma unroll
        for (int j = 0; j < 4; j++) bfr[j] = *(const short8*)&sB[wn + j * 16 + ln][kk + quad * 8];
#pragma unroll
        for (int i = 0; i < 4; i++)
#pragma unroll
          for (int j = 0; j < 4; j++)
            acc[i][j] = __builtin_amdgcn_mfma_f32_16x16x32_bf16(bfr[j], a[i], acc[i][j], 0, 0, 0);
      }
    } else {
#pragma unroll
      for (int kk = 0; kk < 64; kk += 32) {
        short8 a[4], bfr[4];
#pragma unroll
        for (int i = 0; i < 4; i++) a[i] = *(const short8*)&sA[wm + i * 16 + ln][kk + quad * 8];
#pragma unroll
        for (int j = 0; j < 4; j++) bfr[j] = *(const short8*)&sB[wn + j * 16 + ln][kk + quad * 8];
#pragma unroll
        for (int i = 0; i < 4; i++)
#pragma unroll
          for (int j = 0; j < 4; j++)
            acc[i][j] = __builtin_amdgcn_mfma_f32_16x16x32_bf16(a[i], bfr[j], acc[i][j], 0, 0, 0);
      }
    }
    __syncthreads();
  }
  if (z == 2) {
    // C mapping (swapped): row = quad*4+r -> channel n, col = ln -> token m
#pragma unroll
    for (int i = 0; i < 4; i++)
#pragma unroll
      for (int j = 0; j < 4; j++)
#pragma unroll
        for (int r = 0; r < 4; r++) {
          int n = n0 + wn + j * 16 + quad * 4 + r;   // channel
          int m = m0 + wm + i * 16 + ln;             // token (contiguous/lane)
          int bb = m >> 10, s = m & 1023, h = n >> 6, d = n & 63;
          vhT[(((size_t)bb * H_ + h) * DH_ + d) * S_ + s] = f2b(acc[i][j][r]);
        }
  } else {
#pragma unroll
    for (int i = 0; i < 4; i++)
#pragma unroll
      for (int j = 0; j < 4; j++)
#pragma unroll
        for (int r = 0; r < 4; r++) {
          int m = m0 + wm + i * 16 + quad * 4 + r;   // token
          int n = n0 + wn + j * 16 + ln;             // channel (contiguous/lane)
          int bb = m >> 10, s = m & 1023, h = n >> 6, d = n & 63;
          u16 val = f2b(acc[i][j][r]);
          if (z == 0) qh[(((size_t)bb * H_ + h) * S_ + s) * DH_ + d] = val;
          else        kh[(((size_t)bb * H_ + h) * S_ + s) * DH_ + d] = val;
        }
  }
}

// ---------------------------------------------------------------------------
// K2: attention, 16 q-rows/block, 4 waves, strip 33.5 KB => 4 blocks/CU.
// Grid 4096, XCD head-grouping: bh = (wg&7)*8 | (wg>>3)&7.
// A: swapped QK^T -> C[k_sub][q], one ds_write_b64 per MFMA pair.
// B: masked softmax; mask row = ONE coalesced b64 load (pre-permuted pmT),
//    value IS mbits. NT store of fp32 probs.
// C: PV, dual accumulators; V-frags straight from vhT (L2-resident).
// ---------------------------------------------------------------------------
__global__ __launch_bounds__(256) void attn_kernel(
    const u16* __restrict__ qh, const u16* __restrict__ kh,
    const u16* __restrict__ vhT, const unsigned char* __restrict__ pmask,
    float* __restrict__ attn_out, u16* __restrict__ ctx)
{
  __shared__ u16 s_p[16][1048];   // 33.5 KB
  const int t = threadIdx.x;
  const int w = t >> 6, ln = t & 15, quad = (t & 63) >> 4;
  const int wg = blockIdx.x;
  const int bh = ((wg & 7) << 3) | ((wg >> 3) & 7);   // bijective XCD grouping
  const int b = bh >> 4, h = bh & 15;
  const int q0 = (wg >> 6) * 16;

  // Q B-fragments straight from global: row=ln (q-row), k=quad*8(+32)
  const u16* qbase = qh + ((size_t)bh * S_ + q0) * DH_;
  const short8 qf0 = *(const short8*)&qbase[(size_t)ln * DH_ + quad * 8];
  const short8 qf1 = *(const short8*)&qbase[(size_t)ln * DH_ + 32 + quad * 8];

  // ---- Phase A: scores; wave w owns k-cols [w*256, w*256+256) ----
  const u16* kbase = kh + (size_t)bh * S_ * DH_;
#pragma unroll
  for (int ck = 0; ck < 16; ck++) {
    int n = w * 256 + ck * 16;
    const u16* krow = &kbase[(size_t)(n + ln) * DH_];
    short8 kb0 = *(const short8*)&krow[quad * 8];
    short8 kb1 = *(const short8*)&krow[32 + quad * 8];
    f32x4 acc = {};
    acc = __builtin_amdgcn_mfma_f32_16x16x32_bf16(kb0, qf0, acc, 0, 0, 0);
    acc = __builtin_amdgcn_mfma_f32_16x16x32_bf16(kb1, qf1, acc, 0, 0, 0);
    // C[k_sub][q]: k = n + quad*4 + r (consecutive in r), q = ln
    short4v pk;
#pragma unroll
    for (int r = 0; r < 4; r++) pk[r] = (short)f2b(acc[r] * 0.03125f);
    *(short4v*)&s_p[ln][n + quad * 4] = pk;   // one b64 store
  }
  __syncthreads();

  // ---- Phase B: mask + softmax + attn output (16 threads per q-row) ----
  {
    const int r  = t >> 4;    // q-row 0..15
    const int cg = t & 15;    // column group: cols cg*8 + 128*i
    // permuted mask layout: one coalesced b64 = all 8 bytes this thread needs
    const unsigned long long mbits =
        *(const unsigned long long*)&pmask[((size_t)b * S_ + q0 + r) * 128 + cg * 8];
    const u16* prow = s_p[r];
    short8 sv[8];
    float mx = -1e30f;
#pragma unroll
    for (int i = 0; i < 8; i++) {
      int c = cg * 8 + i * 128;
      sv[i] = *(const short8*)&prow[c];
      unsigned mb = (unsigned)(mbits >> (i * 8)) & 0xffu;
#pragma unroll
      for (int j = 0; j < 8; j++) {
        float sval = b2f((u16)sv[i][j]);
        mx = fmaxf(mx, ((mb >> j) & 1) ? -1e30f : sval);   // branchless
      }
    }
#pragma unroll
    for (int off = 8; off >= 1; off >>= 1) mx = fmaxf(mx, __shfl_xor(mx, off));
    float l = 0.f;
#pragma unroll
    for (int i = 0; i < 8; i++) {
      short8 pk;
#pragma unroll
      for (int j = 0; j < 8; j++) {
        float p = ((mbits >> (i * 8 + j)) & 1) ? 0.f
                  : __expf(b2f((u16)sv[i][j]) - mx);
        l += p;
        pk[j] = (short)f2b(p);
      }
      sv[i] = pk;   // regs now hold p (bf16)
    }
#pragma unroll
    for (int off = 8; off >= 1; off >>= 1) l += __shfl_xor(l, off);
    float rinv = (l > 0.f) ? 1.0f / l : 0.f;
    float* arow = attn_out + ((size_t)bh * S_ + q0 + r) * S_;
    u16* prw = s_p[r];
#pragma unroll
    for (int i = 0; i < 8; i++) {
      int c = cg * 8 + i * 128;
      f32x4 o0, o1; short8 pn;
#pragma unroll
      for (int j = 0; j < 8; j++) {
        float pv = b2f((u16)sv[i][j]) * rinv;
        if (j < 4) o0[j] = pv; else o1[j - 4] = pv;
        pn[j] = (short)f2b(pv);
      }
      __builtin_nontemporal_store(o0, (f32x4*)&arow[c]);
      __builtin_nontemporal_store(o1, (f32x4*)&arow[c + 4]);
      *(short8*)&prw[c] = pn;
    }
  }
  __syncthreads();

  // ---- Phase C: ctx = attn @ vh; wave w owns out cols d in [w*16, w*16+16) --
  f32x4 accC0 = {}, accC1 = {};
  const u16* vrow = vhT + ((size_t)bh * DH_ + w * 16 + ln) * S_;
  const u16* prow = s_p[ln];
#pragma unroll 4
  for (int kk = 0; kk < 1024; kk += 64) {
    short8 ap0 = *(const short8*)&prow[kk + quad * 8];
    short8 ap1 = *(const short8*)&prow[kk + 32 + quad * 8];
    short8 bv0 = *(const short8*)&vrow[kk + quad * 8];
    short8 bv1 = *(const short8*)&vrow[kk + 32 + quad * 8];
    accC0 = __builtin_amdgcn_mfma_f32_16x16x32_bf16(ap0, bv0, accC0, 0, 0, 0);
    accC1 = __builtin_amdgcn_mfma_f32_16x16x32_bf16(ap1, bv1, accC1, 0, 0, 0);
  }
  f32x4 accC = accC0 + accC1;
#pragma unroll
  for (int r = 0; r < 4; r++) {
    int qrow = q0 + quad * 4 + r;
    ctx[((size_t)b * S_ + qrow) * D_ + h * DH_ + w * 16 + ln] = f2b(accC[r]);
  }
}

// ---------------------------------------------------------------------------
// K3: out = ctx @ Wd^T + bd (fp32 out, NT stores). m97-style GEMM skeleton.
// ---------------------------------------------------------------------------
__global__ __launch_bounds__(256) void outproj_kernel(
    const u16* __restrict__ ctx, const u16* __restrict__ Wdb,
    const float* __restrict__ bd, float* __restrict__ out)
{
  __shared__ u16 sA[128][64];
  __shared__ u16 sB[128][64];
  const int t = threadIdx.x;
  const int w = t >> 6, ln = t & 15, quad = (t & 63) >> 4;
  const int wm = (w >> 1) * 64, wn = (w & 1) * 64;
  const int n0 = blockIdx.x * 128;
  const int m0 = blockIdx.y * 128;
  const int lrow = (t & 63) >> 3;
  const int lcol = (t & 7) * 8;

  f32x4 acc[4][4] = {};
  for (int kc = 0; kc < 1024; kc += 64) {
#pragma unroll
    for (int i = 0; i < 4; i++) {
      const int r0 = w * 32 + i * 8;
      __builtin_amdgcn_global_load_lds(
          (gas1)&ctx[(size_t)(m0 + r0 + lrow) * 1024 + kc + lcol],
          (las3)(void*)&sA[r0][0], 16, 0, 0);
      __builtin_amdgcn_global_load_lds(
          (gas1)&Wdb[(size_t)(n0 + r0 + lrow) * 1024 + kc + lcol],
          (las3)(void*)&sB[r0][0], 16, 0, 0);
    }
    asm volatile("s_waitcnt vmcnt(0)" ::: "memory");
    __syncthreads();
#pragma unroll
    for (int kk = 0; kk < 64; kk += 32) {
      short8 a[4], bfr[4];
#pragma unroll
      for (int i = 0; i < 4; i++) a[i] = *(const short8*)&sA[wm + i * 16 + ln][kk + quad * 8];
#pragma unroll
      for (int j = 0; j < 4; j++) bfr[j] = *(const short8*)&sB[wn + j * 16 + ln][kk + quad * 8];
#pragma unroll
      for (int i = 0; i < 4; i++)
#pragma unroll
        for (int j = 0; j < 4; j++)
          acc[i][j] = __builtin_amdgcn_mfma_f32_16x16x32_bf16(a[i], bfr[j], acc[i][j], 0, 0, 0);
    }
    __syncthreads();
  }
#pragma unroll
  for (int i = 0; i < 4; i++)
#pragma unroll
    for (int j = 0; j < 4; j++)
#pragma unroll
      for (int r = 0; r < 4; r++) {
        int m = m0 + wm + i * 16 + quad * 4 + r;
        int n = n0 + wn + j * 16 + ln;
        __builtin_nontemporal_store(acc[i][j][r] + bd[n], &out[(size_t)m * 1024 + n]);
      }
}

extern "C" void kernel_launch(void* const* d_in, const int* in_sizes, int n_in,
                              void* d_out, int out_size, void* d_ws, size_t ws_size,
                              hipStream_t stream) {
  const float* q    = (const float*)d_in[0];
  const float* k    = (const float*)d_in[1];
  const float* v    = (const float*)d_in[2];
  const int*   mask = (const int*)d_in[3];
  const float* Wq   = (const float*)d_in[4];
  const float* Wk   = (const float*)d_in[5];
  const float* Wv   = (const float*)d_in[6];
  const float* Wd   = (const float*)d_in[7];
  const float* bd   = (const float*)d_in[8];

  float* out  = (float*)d_out;
  float* attn = out + NOUT_;

  u16* ws   = (u16*)d_ws;
  u16* Qb   = ws;                    // 3x NQ_ bf16 inputs
  u16* Kb   = ws + (size_t)NQ_;
  u16* Vb   = ws + 2 * (size_t)NQ_;
  u16* Wqb  = ws + 3 * (size_t)NQ_;  // 4x NW_ bf16 weights
  u16* Wkb  = Wqb + (size_t)NW_;
  u16* Wvb  = Wqb + 2 * (size_t)NW_;
  u16* Wdb  = Wqb + 3 * (size_t)NW_;
  u16* qh   = Wqb + 4 * (size_t)NW_; // 3x NQ_ projected tensors
  u16* kh   = qh + (size_t)NQ_;
  u16* vhT  = qh + 2 * (size_t)NQ_;
  unsigned char* pm = (unsigned char*)(qh + 3 * (size_t)NQ_);  // 512 KB bitmap
  u16* ctx  = Qb;                    // alias: Qb dead after proj (stream-ordered)

  convert_kernel<<<dim3(2048, 8), 256, 0, stream>>>(q, k, v, Wq, Wk, Wv, Wd, mask,
                                                    Qb, Kb, Vb, Wqb, Wkb, Wvb, Wdb, pm);
  proj_kernel<<<dim3(24, 32), 256, 0, stream>>>(Qb, Kb, Vb, Wqb, Wkb, Wvb, qh, kh, vhT);
  attn_kernel<<<dim3(4096), 256, 0, stream>>>(qh, kh, vhT, pm, attn, ctx);
  outproj_kernel<<<dim3(8, 32), 256, 0, stream>>>(ctx, Wdb, bd, out);
}